// Round 6
// baseline (78.473 us; speedup 1.0000x reference)
//
#include <hip/hip_runtime.h>

// PoolObj: ball-query (annulus) neighbor-count downsampling + gather.
// B=4, N=4096, D=64, K=2048. Out = concat(new_xyz [B,K,3], new_points [B,K,D]).
//
// Fixed harness overhead (268MB ws 0xAA fill @ ~80% HBM peak = 41us, plus
// out poison / input restores / replay gaps) ~= 75us of the measured total;
// our kernels are ~2-4us of it (v5 measured 76.99 total).
//
// v6b: same exact spatial-grid algorithm (16^3 cells, cell 0.0625 > R; the
// 27-neighborhood pruning is EXACT: skipped pairs have true d2 >= 0.0039 vs
// R2=0.0025, far beyond fp rounding ~1e-6). Tested pairs use the verified
// bit-identical rn chain (absmax=0 in v2..v5):
//   dot = (x*x' + y*y') + z*z'   (__fmul_rn/__fadd_rn)
//   d2  = fma(dot, -2, sq_i + sq_j)   [2*dot exact -> same single rounding]
// Annulus test = ONE unsigned range-check on float bits. cell = floor(16x)
// exact. Counts are integer sums -> bin order cannot change output bits.
//
// v6 structural changes (no math change):
//   K2 ranking reworked to ballot scheme: lane = key, point broadcast via
//   readlane. ONE v_cmp (ballot) covers 64 key-compares; popcount+accumulate
//   ride the SCALAR pipe (s_bcnt/s_add co-issue with VALU). The per-point
//   rank r is wave-uniform, so it lands in lane p via cndmask select
//   (v6b fix: __builtin_amdgcn_writelane does not exist on this ROCm; the
//   select is +1 VALU/point, equivalent semantics). Identical int compares
//   on identical integers -> bit-exact ranks. Each key is read once per
//   block: the LDS key stage + one barrier are gone; waves load slices
//   straight from L2-hot keys[].
//   Ka loads coords as float4 per plane (thread owns 4 consecutive points):
//   3 vmem insts instead of 12. Within-cell order from atomics stays
//   arbitrary -- counting is order-independent, so no output change.
// key = cnt<<12 | (4095-i): one int compare == lax.top_k (count desc, index
// asc) order; ranks are a permutation so each output slot written once.
// grid.sync() measured ~45us/sync on gfx950 -- kernel boundaries are the
// cheap global barriers; do NOT re-fuse (bin->count->rank each need a
// global sync).

#pragma clang fp contract(off)

#define BN 4
#define NPTS 4096
#define ND 64
#define KSEL 2048
#define R2 0.0025f   // RADIUS^2
#define M2 0.0004f   // MIN_RADIUS^2
#define NCELL 4096   // 16^3
#define CS_STRIDE 4100

typedef unsigned int u32;
typedef unsigned short u16;
typedef unsigned long long u64;

// ws layout (bytes); ws poisoned 0xAA each replay -- every slot read below
// is written first by Ka/Kb in the same replay.
#define OFF_SORTED 0                              // float4 [BN][NPTS] = 256KB
#define OFF_SIDX   262144                         // u16   [BN][NPTS] =  32KB
#define OFF_CS     294912                         // u32   [BN][CS_STRIDE]
#define OFF_KEYS   360512                         // u32   [BN][NPTS] =  64KB

// Ka: one block per batch. Histogram -> scan -> scatter.
__global__ __launch_bounds__(1024) void bin_kernel(
        const float* __restrict__ xyz, float4* __restrict__ sorted,
        u16* __restrict__ sidx, u32* __restrict__ cellstart) {
    __shared__ u32 hist[NCELL];
    __shared__ u32 wtot[16];
    const int b = blockIdx.x;
    const float* base = xyz + (size_t)b * 3 * NPTS;
    const int tid = threadIdx.x;
    ((int4*)hist)[tid] = make_int4(0, 0, 0, 0);
    __syncthreads();

    // thread owns 4 consecutive points: one float4 per plane.
    float4 xv = ((const float4*)base)[tid];
    float4 yv = ((const float4*)(base + NPTS))[tid];
    float4 zv = ((const float4*)(base + 2 * NPTS))[tid];
    const float xk[4] = {xv.x, xv.y, xv.z, xv.w};
    const float yk[4] = {yv.x, yv.y, yv.z, yv.w};
    const float zk[4] = {zv.x, zv.y, zv.z, zv.w};

    u32 crk[4];                       // (cell<<16)|rank-in-cell, both <4096
    #pragma unroll
    for (int k = 0; k < 4; ++k) {
        // exact: x*16 is an exponent shift for x in [0,1)
        int c = (int)(xk[k] * 16.0f) | ((int)(yk[k] * 16.0f) << 4)
                                     | ((int)(zk[k] * 16.0f) << 8);
        u32 r = atomicAdd(&hist[c], 1u);
        crk[k] = ((u32)c << 16) | r;
    }
    __syncthreads();

    // exclusive scan of hist[4096]: 4 consecutive bins/thread, wave shfl scan,
    // 16 wave totals through LDS. cellstart written inline with the fixup.
    u32 v4[4], sum = 0;
    #pragma unroll
    for (int k = 0; k < 4; ++k) { v4[k] = hist[tid * 4 + k]; sum += v4[k]; }
    const int lane = tid & 63, w = tid >> 6;
    u32 incl = sum;
    #pragma unroll
    for (int d = 1; d < 64; d <<= 1) {
        u32 t = __shfl_up(incl, d, 64);
        if (lane >= d) incl += t;
    }
    if (lane == 63) wtot[w] = incl;
    __syncthreads();
    u32 woff = 0;
    #pragma unroll
    for (int ww = 0; ww < 16; ++ww) woff += (ww < w) ? wtot[ww] : 0u;
    u32* csb = cellstart + b * CS_STRIDE;
    u32 run = woff + incl - sum;      // exclusive start of this thread's bins
    #pragma unroll
    for (int k = 0; k < 4; ++k) {
        u32 h = v4[k];
        hist[tid * 4 + k] = run;
        csb[tid * 4 + k]  = run;
        run += h;
    }
    if (tid == 0) csb[NCELL] = NPTS;
    __syncthreads();

    // scatter from registers: pos = cellstart[c] + rank; sq via the
    // reference rn chain (stored in .w, consumed by Kb's d2).
    #pragma unroll
    for (int k = 0; k < 4; ++k) {
        float x = xk[k], y = yk[k], z = zk[k];
        float sq = __fadd_rn(__fadd_rn(__fmul_rn(x, x), __fmul_rn(y, y)),
                             __fmul_rn(z, z));
        u32 c = crk[k] >> 16, r = crk[k] & 0xFFFFu;
        u32 pos = hist[c] + r;
        sorted[((size_t)b << 12) + pos] = make_float4(x, y, z, sq);
        sidx[((size_t)b << 12) + pos]   = (u16)(tid * 4 + k);
    }
}

// Kb: block = 192 threads = 3 waves; wave w = z-slab (cz+w-1) for 64
// consecutive sorted points. Partials combined in-block -> final key,
// stored at keys[ORIG] so K2's loads are fully linear.
// grid = BN*NPTS/64 = 256 blocks.
__global__ __launch_bounds__(192) void count_key_kernel(
        const float4* __restrict__ sorted, const u32* __restrict__ cellstart,
        const u16* __restrict__ sidx, u32* __restrict__ keys) {
    __shared__ u32 spart[3][64];
    const int tid  = threadIdx.x;
    const int lane = tid & 63;
    const int w    = tid >> 6;            // 0..2 (z-slab)
    const int gp   = blockIdx.x * 64;     // first sorted point of this block
    const int b    = gp >> 12;
    const int p    = (gp & (NPTS - 1)) + lane;

    // issue-early: orig index load rides under the count loop's latency.
    const int orig = sidx[((size_t)b << 12) + p];

    const float4* sb = sorted + ((size_t)b << 12);
    const float4 v = sb[p];
    const int cx = (int)(v.x * 16.0f);
    const int cy = (int)(v.y * 16.0f);
    const int cz = (int)(v.z * 16.0f);
    const int zz = cz + w - 1;

    const int      m2i1  = __float_as_int(M2) + 1;
    const unsigned range = (unsigned)(__float_as_int(R2) - __float_as_int(M2)) - 1u;

    u32 cnt = 0;
    if ((unsigned)zz < 16u) {
        const u32* cs = cellstart + b * CS_STRIDE + (zz << 8);
        const int x0  = (cx > 0)  ? cx - 1 : 0;
        const int x1e = ((cx < 15) ? cx + 1 : 15) + 1;
        const int y0  = (cy > 0)  ? cy - 1 : 0;
        const int y1  = (cy < 15) ? cy + 1 : 15;
        for (int y = y0; y <= y1; ++y) {
            // 3 x-neighbor cells are consecutive in the flat index: one
            // [s,e) member segment (flat cellstart is monotone; x1e=16
            // correctly lands on the next row's start, csb[4096]=NPTS).
            u32 s = cs[(y << 4) + x0];
            u32 e = cs[(y << 4) + x1e];
            for (u32 q = s; q < e; ++q) {
                float4 u = sb[q];
                float dot = __fadd_rn(__fadd_rn(__fmul_rn(v.x, u.x),
                                                __fmul_rn(v.y, u.y)),
                                      __fmul_rn(v.z, u.z));
                float spw = __fadd_rn(v.w, u.w);
                float d2  = __builtin_fmaf(dot, -2.0f, spw);
                // self-pair (q==p): dot==sq exactly, spw==2sq -> d2==0 ->
                // excluded, same as reference.
                cnt += ((unsigned)(__float_as_int(d2) - m2i1) < range) ? 1u : 0u;
            }
        }
    }
    spart[w][lane] = cnt;
    __syncthreads();
    if (tid < 64) {
        u32 c = spart[0][lane] + spart[1][lane] + spart[2][lane];
        // final key stored by ORIG index; low 12 bits encode 4095-orig.
        keys[((size_t)b << 12) + orig] = (c << 12) | (u32)(NPTS - 1 - orig);
    }
}

// K2: grid = BN*64 = 256 blocks x 512 threads; block owns 64 consecutive
// orig-i of batch b.
__global__ __launch_bounds__(512) void rank_gather_kernel(
        const float* __restrict__ xyz, const float* __restrict__ points,
        const u32* __restrict__ keys, float* __restrict__ out) {
    __shared__ float sfeat[ND][68];     // transpose tile (pad 68: 68%32==4
    __shared__ int spr[8][64];          //   -> 2-way LDS = free)
    __shared__ int srank[64];
    const int b     = blockIdx.x >> 6;
    const int tbase = (blockIdx.x & 63) * 64;
    const int tid   = threadIdx.x;
    const int ii    = tid & 63;
    const int q     = tid >> 6;          // 0..7

    // ---- issue-early (T14): phase-C feature loads + tid<64 xyz loads into
    // registers NOW; HBM latency hides under the ranking phase.
    float fv[8];
    {
        const float* pb = points + ((size_t)b * ND + q) * NPTS + tbase + ii;
        #pragma unroll
        for (int r8 = 0; r8 < 8; ++r8)
            fv[r8] = pb[(size_t)(8 * r8) * NPTS];
    }
    float x3[3];
    if (tid < 64) {
        const float* xb = xyz + (size_t)b * 3 * NPTS + tbase + tid;
        x3[0] = xb[0]; x3[1] = xb[NPTS]; x3[2] = xb[2 * NPTS];
    }

    // ---- ranking, ballot scheme: lane = key, point broadcast via readlane.
    // Wave q owns key slice [q*512, q*512+512): lane ii holds 8 keys (two
    // int4s). For each owned point p: ki = readlane (uniform SGPR), ONE
    // v_cmp per ballot covers 64 key-compares; popcount+accumulate are
    // SALU (s_bcnt/s_add co-issue with VALU). r is wave-uniform; land it in
    // lane p with a cndmask select (p is an unroll constant). Identical int
    // compares on identical integers -> bit-exact rank.
    {
        const u32* kb = keys + ((size_t)b << 12);
        const int kown = (int)kb[tbase + ii];     // lane ii: key of point ii
        const int4* kq = (const int4*)kb;
        const int4 a = kq[q * 128 + ii];          // keys q*512 + 4*ii ..
        const int4 c = kq[q * 128 + 64 + ii];     // keys q*512+256+4*ii ..
        int vres = 0;
        #pragma unroll
        for (int p = 0; p < 64; ++p) {
            const int ki = __builtin_amdgcn_readlane(kown, p);
            u64 m0 = __ballot(a.x > ki);
            u64 m1 = __ballot(a.y > ki);
            u64 m2 = __ballot(a.z > ki);
            u64 m3 = __ballot(a.w > ki);
            u64 m4 = __ballot(c.x > ki);
            u64 m5 = __ballot(c.y > ki);
            u64 m6 = __ballot(c.z > ki);
            u64 m7 = __ballot(c.w > ki);
            int r = (int)(__popcll(m0) + __popcll(m1) + __popcll(m2) +
                          __popcll(m3) + __popcll(m4) + __popcll(m5) +
                          __popcll(m6) + __popcll(m7));
            vres = (ii == p) ? r : vres;          // lane p keeps r_p
        }
        spr[q][ii] = vres;
    }
    __syncthreads();

    if (tid < 64) {
        const int rank = spr[0][tid] + spr[1][tid] + spr[2][tid] + spr[3][tid]
                       + spr[4][tid] + spr[5][tid] + spr[6][tid] + spr[7][tid];
        srank[tid] = rank;
        if (rank < KSEL) {
            float* o = out + ((size_t)b * KSEL + rank) * 3;
            o[0] = x3[0]; o[1] = x3[1]; o[2] = x3[2];
        }
    }
    __syncthreads();

    // ---- features via LDS transpose (write-late half of T14).
    {
        #pragma unroll
        for (int r8 = 0; r8 < 8; ++r8)
            sfeat[q + 8 * r8][ii] = fv[r8];
    }
    __syncthreads();

    // Write: 4 threads per point (tid<256 keeps the 2-way-free bank
    // pattern), contiguous float4 runs per output row.
    if (tid < 256) {
        const int pt = tid >> 2;        // 0..63
        const int c4 = tid & 3;
        const int rank = srank[pt];
        if (rank < KSEL) {
            float* orow = out + (size_t)BN * KSEL * 3 +
                          ((size_t)b * KSEL + rank) * ND;
            #pragma unroll
            for (int u4 = 0; u4 < 4; ++u4) {
                const int c0 = u4 * 16 + c4 * 4;
                float4 v = make_float4(sfeat[c0 + 0][pt],
                                       sfeat[c0 + 1][pt],
                                       sfeat[c0 + 2][pt],
                                       sfeat[c0 + 3][pt]);
                *(float4*)(orow + c0) = v;
            }
        }
    }
}

extern "C" void kernel_launch(void* const* d_in, const int* in_sizes, int n_in,
                              void* d_out, int out_size, void* d_ws, size_t ws_size,
                              hipStream_t stream) {
    const float* xyz    = (const float*)d_in[0];   // [B, 3, N, 1]
    const float* points = (const float*)d_in[1];   // [B, D, N, 1]
    float* out = (float*)d_out;
    char*  ws  = (char*)d_ws;

    float4* sorted    = (float4*)(ws + OFF_SORTED);
    u16*    sidx      = (u16*)  (ws + OFF_SIDX);
    u32*    cellstart = (u32*)  (ws + OFF_CS);
    u32*    keys      = (u32*)  (ws + OFF_KEYS);

    bin_kernel        <<<BN, 1024, 0, stream>>>(xyz, sorted, sidx, cellstart);
    count_key_kernel  <<<BN * NPTS / 64, 192, 0, stream>>>(sorted, cellstart, sidx, keys);
    rank_gather_kernel<<<BN * 64, 512, 0, stream>>>(xyz, points, keys, out);
}

// Round 7
// 76.648 us; speedup vs baseline: 1.0238x; 1.0238x over previous
//
#include <hip/hip_runtime.h>

// PoolObj: ball-query (annulus) neighbor-count downsampling + gather.
// B=4, N=4096, D=64, K=2048. Out = concat(new_xyz [B,K,3], new_points [B,K,D]).
//
// Fixed harness overhead (268MB ws 0xAA fill @ ~80% HBM peak = 41us, plus
// out poison / input restores / replay gaps) ~= 75us of the measured total;
// our kernels are ~2-4us of it (v5 measured 76.99 total; v6b ballot-ranking
// regressed to 78.47 -- the 64-iter readlane chain serializes, REVERTED).
//
// v7 = v5 structure + Ka float4 coord loads. Same exact spatial-grid
// algorithm (16^3 cells, cell 0.0625 > R; 27-neighborhood pruning is EXACT:
// skipped pairs have true d2 >= 0.0039 vs R2=0.0025, far beyond fp rounding
// ~1e-6). Tested pairs use the verified bit-identical rn chain (absmax=0 in
// v2..v6):
//   dot = (x*x' + y*y') + z*z'   (__fmul_rn/__fadd_rn)
//   d2  = fma(dot, -2, sq_i + sq_j)   [2*dot exact -> same single rounding]
// Annulus test = ONE unsigned range-check on float bits. cell = floor(16x)
// exact. Counts are integer sums -> bin order cannot change output bits.
//
// Structure:
//   Ka bin   : 4 blocks x 1024. float4 coord loads (thread owns 4
//              consecutive points), LDS histogram -> shfl scan -> scatter
//              into cell-sorted float4(x,y,z,sq) + sidx + cellstart.
//   Kb count : 192-thread blocks = 3 waves = 3 z-slabs x 64 sorted points;
//              3x3 consecutive-x cell rows -> one [s,e) segment per row.
//              Partials combined in LDS -> final key stored at keys[ORIG].
//   K2 rank_gather: 512 threads. Linear int4 key loads -> LDS; per-lane
//              compare ranking (8 waves x 128 int4 each, b128 wave-broadcast
//              reads); feature gather via LDS transpose tile, issue-early
//              loads (T14) hide HBM latency under ranking.
// key = cnt<<12 | (4095-i): one int compare == lax.top_k (count desc, index
// asc) order; ranks are a permutation so each output slot written once.
// grid.sync() measured ~45us/sync on gfx950 -- kernel boundaries are the
// cheap global barriers; do NOT re-fuse.
//
// Ranking-scheme note (v6b post-mortem): ballot+readlane ranking (64-point
// loop, 8 ballots/point) is a serial scalar-latency chain -- measured 1.5us
// SLOWER than the per-lane compare loop despite fewer VALU ops. Keep the
// throughput-parallel per-lane scheme.

#pragma clang fp contract(off)

#define BN 4
#define NPTS 4096
#define ND 64
#define KSEL 2048
#define R2 0.0025f   // RADIUS^2
#define M2 0.0004f   // MIN_RADIUS^2
#define NCELL 4096   // 16^3
#define CS_STRIDE 4100

typedef unsigned int u32;
typedef unsigned short u16;

// ws layout (bytes); ws poisoned 0xAA each replay -- every slot read below
// is written first by Ka/Kb in the same replay.
#define OFF_SORTED 0                              // float4 [BN][NPTS] = 256KB
#define OFF_SIDX   262144                         // u16   [BN][NPTS] =  32KB
#define OFF_CS     294912                         // u32   [BN][CS_STRIDE]
#define OFF_KEYS   360512                         // u32   [BN][NPTS] =  64KB

// Ka: one block per batch. Histogram -> scan -> scatter.
__global__ __launch_bounds__(1024) void bin_kernel(
        const float* __restrict__ xyz, float4* __restrict__ sorted,
        u16* __restrict__ sidx, u32* __restrict__ cellstart) {
    __shared__ u32 hist[NCELL];
    __shared__ u32 wtot[16];
    const int b = blockIdx.x;
    const float* base = xyz + (size_t)b * 3 * NPTS;
    const int tid = threadIdx.x;
    ((int4*)hist)[tid] = make_int4(0, 0, 0, 0);
    __syncthreads();

    // thread owns 4 consecutive points: one float4 per plane.
    float4 xv = ((const float4*)base)[tid];
    float4 yv = ((const float4*)(base + NPTS))[tid];
    float4 zv = ((const float4*)(base + 2 * NPTS))[tid];
    const float xk[4] = {xv.x, xv.y, xv.z, xv.w};
    const float yk[4] = {yv.x, yv.y, yv.z, yv.w};
    const float zk[4] = {zv.x, zv.y, zv.z, zv.w};

    u32 crk[4];                       // (cell<<16)|rank-in-cell, both <4096
    #pragma unroll
    for (int k = 0; k < 4; ++k) {
        // exact: x*16 is an exponent shift for x in [0,1)
        int c = (int)(xk[k] * 16.0f) | ((int)(yk[k] * 16.0f) << 4)
                                     | ((int)(zk[k] * 16.0f) << 8);
        u32 r = atomicAdd(&hist[c], 1u);
        crk[k] = ((u32)c << 16) | r;
    }
    __syncthreads();

    // exclusive scan of hist[4096]: 4 consecutive bins/thread, wave shfl scan,
    // 16 wave totals through LDS. cellstart written inline with the fixup.
    u32 v4[4], sum = 0;
    #pragma unroll
    for (int k = 0; k < 4; ++k) { v4[k] = hist[tid * 4 + k]; sum += v4[k]; }
    const int lane = tid & 63, w = tid >> 6;
    u32 incl = sum;
    #pragma unroll
    for (int d = 1; d < 64; d <<= 1) {
        u32 t = __shfl_up(incl, d, 64);
        if (lane >= d) incl += t;
    }
    if (lane == 63) wtot[w] = incl;
    __syncthreads();
    u32 woff = 0;
    #pragma unroll
    for (int ww = 0; ww < 16; ++ww) woff += (ww < w) ? wtot[ww] : 0u;
    u32* csb = cellstart + b * CS_STRIDE;
    u32 run = woff + incl - sum;      // exclusive start of this thread's bins
    #pragma unroll
    for (int k = 0; k < 4; ++k) {
        u32 h = v4[k];
        hist[tid * 4 + k] = run;
        csb[tid * 4 + k]  = run;
        run += h;
    }
    if (tid == 0) csb[NCELL] = NPTS;
    __syncthreads();

    // scatter from registers: pos = cellstart[c] + rank; sq via the
    // reference rn chain (stored in .w, consumed by Kb's d2).
    #pragma unroll
    for (int k = 0; k < 4; ++k) {
        float x = xk[k], y = yk[k], z = zk[k];
        float sq = __fadd_rn(__fadd_rn(__fmul_rn(x, x), __fmul_rn(y, y)),
                             __fmul_rn(z, z));
        u32 c = crk[k] >> 16, r = crk[k] & 0xFFFFu;
        u32 pos = hist[c] + r;
        sorted[((size_t)b << 12) + pos] = make_float4(x, y, z, sq);
        sidx[((size_t)b << 12) + pos]   = (u16)(tid * 4 + k);
    }
}

// Kb: block = 192 threads = 3 waves; wave w = z-slab (cz+w-1) for 64
// consecutive sorted points. Partials combined in-block -> final key,
// stored at keys[ORIG] so K2's load/LDS-fill is fully linear.
// grid = BN*NPTS/64 = 256 blocks.
__global__ __launch_bounds__(192) void count_key_kernel(
        const float4* __restrict__ sorted, const u32* __restrict__ cellstart,
        const u16* __restrict__ sidx, u32* __restrict__ keys) {
    __shared__ u32 spart[3][64];
    const int tid  = threadIdx.x;
    const int lane = tid & 63;
    const int w    = tid >> 6;            // 0..2 (z-slab)
    const int gp   = blockIdx.x * 64;     // first sorted point of this block
    const int b    = gp >> 12;
    const int p    = (gp & (NPTS - 1)) + lane;

    // issue-early: orig index load rides under the count loop's latency.
    const int orig = sidx[((size_t)b << 12) + p];

    const float4* sb = sorted + ((size_t)b << 12);
    const float4 v = sb[p];
    const int cx = (int)(v.x * 16.0f);
    const int cy = (int)(v.y * 16.0f);
    const int cz = (int)(v.z * 16.0f);
    const int zz = cz + w - 1;

    const int      m2i1  = __float_as_int(M2) + 1;
    const unsigned range = (unsigned)(__float_as_int(R2) - __float_as_int(M2)) - 1u;

    u32 cnt = 0;
    if ((unsigned)zz < 16u) {
        const u32* cs = cellstart + b * CS_STRIDE + (zz << 8);
        const int x0  = (cx > 0)  ? cx - 1 : 0;
        const int x1e = ((cx < 15) ? cx + 1 : 15) + 1;
        const int y0  = (cy > 0)  ? cy - 1 : 0;
        const int y1  = (cy < 15) ? cy + 1 : 15;
        for (int y = y0; y <= y1; ++y) {
            // 3 x-neighbor cells are consecutive in the flat index: one
            // [s,e) member segment (flat cellstart is monotone; x1e=16
            // correctly lands on the next row's start, csb[4096]=NPTS).
            u32 s = cs[(y << 4) + x0];
            u32 e = cs[(y << 4) + x1e];
            for (u32 q = s; q < e; ++q) {
                float4 u = sb[q];
                float dot = __fadd_rn(__fadd_rn(__fmul_rn(v.x, u.x),
                                                __fmul_rn(v.y, u.y)),
                                      __fmul_rn(v.z, u.z));
                float spw = __fadd_rn(v.w, u.w);
                float d2  = __builtin_fmaf(dot, -2.0f, spw);
                // self-pair (q==p): dot==sq exactly, spw==2sq -> d2==0 ->
                // excluded, same as reference.
                cnt += ((unsigned)(__float_as_int(d2) - m2i1) < range) ? 1u : 0u;
            }
        }
    }
    spart[w][lane] = cnt;
    __syncthreads();
    if (tid < 64) {
        u32 c = spart[0][lane] + spart[1][lane] + spart[2][lane];
        // final key stored by ORIG index; low 12 bits encode 4095-orig.
        keys[((size_t)b << 12) + orig] = (c << 12) | (u32)(NPTS - 1 - orig);
    }
}

// K2: grid = BN*64 = 256 blocks x 512 threads; block owns 64 consecutive
// orig-i of batch b.
__global__ __launch_bounds__(512) void rank_gather_kernel(
        const float* __restrict__ xyz, const float* __restrict__ points,
        const u32* __restrict__ keys, float* __restrict__ out) {
    __shared__ union {
        alignas(16) int skey[NPTS];     // phases A/B: 16 KB keys
        float sfeat[ND][68];            // phase C: transpose tile (pad 68:
    } sh;                               //   68%32==4 -> 2-way LDS = free)
    __shared__ int spr[8][64];
    __shared__ int srank[64];
    const int b     = blockIdx.x >> 6;
    const int tbase = (blockIdx.x & 63) * 64;
    const int tid   = threadIdx.x;
    const int ii    = tid & 63;
    const int q     = tid >> 6;          // 0..7

    // ---- issue-early (T14): phase-C feature loads + tid<64 xyz loads into
    // registers NOW; HBM latency hides under phases A/B. ds/global writes
    // stay in their phases.
    float fv[8];
    {
        const float* pb = points + ((size_t)b * ND + q) * NPTS + tbase + ii;
        #pragma unroll
        for (int r8 = 0; r8 < 8; ++r8)
            fv[r8] = pb[(size_t)(8 * r8) * NPTS];
    }
    float x3[3];
    if (tid < 64) {
        const float* xb = xyz + (size_t)b * 3 * NPTS + tbase + tid;
        x3[0] = xb[0]; x3[1] = xb[NPTS]; x3[2] = xb[2 * NPTS];
    }

    // ---- phase A: fully linear -- coalesced int4 loads, b128 LDS stores.
    {
        const int4* kq = (const int4*)(keys + ((size_t)b << 12));
        #pragma unroll
        for (int r = 0; r < 2; ++r)
            ((int4*)sh.skey)[r * 512 + tid] = kq[r * 512 + tid];
    }
    __syncthreads();

    // ---- phase B: rank own 64 points (wave-broadcast b128 reads; 8 slices)
    {
        const int ki = sh.skey[tbase + ii];
        const int4* sk4 = (const int4*)sh.skey;
        int r = 0;
        #pragma unroll 8
        for (int jj = q * 128; jj < q * 128 + 128; ++jj) {
            int4 v = sk4[jj];
            r += (v.x > ki) ? 1 : 0;
            r += (v.y > ki) ? 1 : 0;
            r += (v.z > ki) ? 1 : 0;
            r += (v.w > ki) ? 1 : 0;
        }
        spr[q][ii] = r;
    }
    __syncthreads();

    if (tid < 64) {
        const int rank = spr[0][tid] + spr[1][tid] + spr[2][tid] + spr[3][tid]
                       + spr[4][tid] + spr[5][tid] + spr[6][tid] + spr[7][tid];
        srank[tid] = rank;
        if (rank < KSEL) {
            float* o = out + ((size_t)b * KSEL + rank) * 3;
            o[0] = x3[0]; o[1] = x3[1]; o[2] = x3[2];
        }
    }
    __syncthreads();   // also: skey dead from here, sfeat may overwrite

    // ---- phase C: features via LDS transpose (write-late half of T14).
    {
        #pragma unroll
        for (int r8 = 0; r8 < 8; ++r8)
            sh.sfeat[q + 8 * r8][ii] = fv[r8];
    }
    __syncthreads();

    // Write: 4 threads per point (tid<256 keeps the 2-way-free bank
    // pattern), contiguous float4 runs per output row.
    if (tid < 256) {
        const int pt = tid >> 2;        // 0..63
        const int c4 = tid & 3;
        const int rank = srank[pt];
        if (rank < KSEL) {
            float* orow = out + (size_t)BN * KSEL * 3 +
                          ((size_t)b * KSEL + rank) * ND;
            #pragma unroll
            for (int u4 = 0; u4 < 4; ++u4) {
                const int c0 = u4 * 16 + c4 * 4;
                float4 v = make_float4(sh.sfeat[c0 + 0][pt],
                                       sh.sfeat[c0 + 1][pt],
                                       sh.sfeat[c0 + 2][pt],
                                       sh.sfeat[c0 + 3][pt]);
                *(float4*)(orow + c0) = v;
            }
        }
    }
}

extern "C" void kernel_launch(void* const* d_in, const int* in_sizes, int n_in,
                              void* d_out, int out_size, void* d_ws, size_t ws_size,
                              hipStream_t stream) {
    const float* xyz    = (const float*)d_in[0];   // [B, 3, N, 1]
    const float* points = (const float*)d_in[1];   // [B, D, N, 1]
    float* out = (float*)d_out;
    char*  ws  = (char*)d_ws;

    float4* sorted    = (float4*)(ws + OFF_SORTED);
    u16*    sidx      = (u16*)  (ws + OFF_SIDX);
    u32*    cellstart = (u32*)  (ws + OFF_CS);
    u32*    keys      = (u32*)  (ws + OFF_KEYS);

    bin_kernel        <<<BN, 1024, 0, stream>>>(xyz, sorted, sidx, cellstart);
    count_key_kernel  <<<BN * NPTS / 64, 192, 0, stream>>>(sorted, cellstart, sidx, keys);
    rank_gather_kernel<<<BN * 64, 512, 0, stream>>>(xyz, points, keys, out);
}